// Round 7
// baseline (70.699 us; speedup 1.0000x reference)
//
#include <hip/hip_runtime.h>

// x (16384 x 4096 fp32), W (4096 x 4096 fp32)
// out[b] = 0.75 * dot(x[b,:], colsum(W)), shape (16384,1) fp32.
// Memory-bound: 320 MB compulsory read -> ~51 us roofline @ 6.3 TB/s.

#define N_COLS 4096
#define BATCH  16384
#define SCALE  0.75f   // SCALING_FACTOR / 2.0

typedef float f32x4 __attribute__((ext_vector_type(4)));

__device__ __forceinline__ f32x4 ntload4(const float* p) {
    return __builtin_nontemporal_load(reinterpret_cast<const f32x4*>(p));
}

// ---------------- Kernel 1: column-sum of W into ws[0..4095] ----------------
// v3: contiguous + flat-batch. grid = (4 col-tiles, 128 row-chunks) = 512
// blocks (2/CU, 8 waves/CU). Thread owns 4 consecutive cols (f32x4);
// wave-instruction covers 1 KB contiguous. 32 rows/thread issued as 4 flat
// batches of 8 independent loads (8 KB/wave in flight). 4 atomicAdds/thread,
// 128 contenders/address (proven cheap in R1/R3). ws zeroed via memset.
__global__ __launch_bounds__(256) void colsum_kernel(const float* __restrict__ W,
                                                     float* __restrict__ ws) {
    const int colBase = blockIdx.x * 1024 + threadIdx.x * 4;
    const int row0    = blockIdx.y * 32;

    f32x4 acc = {0.f, 0.f, 0.f, 0.f};
#pragma unroll
    for (int kb = 0; kb < 4; ++kb) {
        f32x4 v[8];
#pragma unroll
        for (int r = 0; r < 8; ++r)
            v[r] = ntload4(&W[(size_t)(row0 + kb * 8 + r) * N_COLS + colBase]);
#pragma unroll
        for (int r = 0; r < 8; ++r)
            acc += v[r];
    }
    atomicAdd(&ws[colBase + 0], acc.x);
    atomicAdd(&ws[colBase + 1], acc.y);
    atomicAdd(&ws[colBase + 2], acc.z);
    atomicAdd(&ws[colBase + 3], acc.w);
}

// ---------------- Kernel 2: out[b] = SCALE * dot(x[b,:], ws) ----------------
// EXACT R6 version. Wave owns a full row (2 rows sequentially); ws hoisted
// into 16 persistent f32x4 regs; 16 independent nt loads per row as one
// flat batch; then dot + wave reduction.
__global__ __launch_bounds__(256) void rowdot2_kernel(const float* __restrict__ x,
                                                      const float* __restrict__ ws,
                                                      float* __restrict__ out) {
    const int lane = threadIdx.x & 63;
    const int wid  = blockIdx.x * 4 + (threadIdx.x >> 6);   // 0..8191

    f32x4 c[16];
#pragma unroll
    for (int i = 0; i < 16; ++i)
        c[i] = *reinterpret_cast<const f32x4*>(&ws[(i * 64 + lane) * 4]);

#pragma unroll
    for (int rep = 0; rep < 2; ++rep) {
        const int row = wid + rep * 8192;
        const float* __restrict__ xr = x + (size_t)row * N_COLS;

        f32x4 v[16];
#pragma unroll
        for (int i = 0; i < 16; ++i)
            v[i] = ntload4(&xr[(i * 64 + lane) * 4]);

        float acc = 0.f;
#pragma unroll
        for (int i = 0; i < 16; ++i)
            acc += v[i].x * c[i].x + v[i].y * c[i].y +
                   v[i].z * c[i].z + v[i].w * c[i].w;

#pragma unroll
        for (int off = 32; off >= 1; off >>= 1)
            acc += __shfl_down(acc, off, 64);

        if (lane == 0) out[row] = acc * SCALE;
    }
}

extern "C" void kernel_launch(void* const* d_in, const int* in_sizes, int n_in,
                              void* d_out, int out_size, void* d_ws, size_t ws_size,
                              hipStream_t stream) {
    const float* x = (const float*)d_in[0];   // (16384, 4096)
    const float* W = (const float*)d_in[1];   // (4096, 4096)
    float* out = (float*)d_out;               // (16384, 1)
    float* ws  = (float*)d_ws;

    (void)hipMemsetAsync(ws, 0, N_COLS * sizeof(float), stream);
    colsum_kernel<<<dim3(4, 128), 256, 0, stream>>>(W, ws);
    rowdot2_kernel<<<2048, 256, 0, stream>>>(x, ws, out);
}